// Round 9
// baseline (274.445 us; speedup 1.0000x reference)
//
#include <hip/hip_runtime.h>
#include <limits.h>
#include <math.h>
#include <stdint.h>

#define WOS_ZERO_TOL 1e-6f
#define STRIDE 57   // odd stride: rows start on distinct bank pairs

// One wave (64 lanes) per pixel; nc processed in TWO groups of 8 so the
// sorted-column LDS array is half size -> 4.1 KB/wave -> 8 blocks/CU
// (32 waves/CU, 100% occupancy; round 8 was latency-bound at ~5 waves/SIMD).
//
// Phase 1 (per nc in group): lane d owns candidate d (d<27: patch value,
//   d>=27: negated). Stable descending rank via u64 key
//   (ordered_float :: 63-lane) — bit-exact vs jnp stable argsort (verified
//   rounds 2/4/5/6/7/8). Keys broadcast through LDS (publish b64, read back
//   as ulonglong2/b128 at wave-uniform addresses, 27 reads); VALU per pair =
//   2x (v_cmp_gt_u64 vcc + v_addc). Scatter float2{wsel,mxv} into sorted
//   column s_wm[wid][i][rank] with ONE ds_write_b64 (ranks distinct).
// Phase 2 (per group, transposed): lane nc8 = lane&7 walks the 54 sorted
//   slots once — sequential f32 adds, association order identical to
//   np.cumsum. Selection in-loop: take = nz && (acc<=bias || !found) keeps
//   the LAST nz with acc<=bias, or the FIRST nz if none (acc is monotone
//   over nz slots -> exactly the reference's clamped li). No final gather.
// Same-wave LDS RAW/WAR ordering (publish->read, scatter->scan, group 0->1
//   overwrite) is guaranteed by in-order per-wave LDS + compiler lgkmcnt.
__global__ __launch_bounds__(256, 8) void wos_kernel(
    const float* __restrict__ x,       // (8,3,64,64)
    const float* __restrict__ mask,    // (16,54)
    const float* __restrict__ weight,  // (16,54)
    const float* __restrict__ bias,    // (16,1)
    float* __restrict__ out)           // flat: [pixel*16 + nc]
{
    __shared__ float2 s_wm[4][8][STRIDE];
    __shared__ unsigned long long s_key[4][64];

    const int lane = threadIdx.x & 63;
    const int wid  = threadIdx.x >> 6;
    const int p    = blockIdx.x * 4 + wid;   // pixel in [0, 32768)
    const int b    = p >> 12;
    const int l    = p & 4095;
    const int h    = l >> 6;
    const int w    = l & 63;

    // Gather this lane's patch value (zero padding at borders).
    float inp = 0.0f;
    if (lane < 54) {
        int dm  = (lane < 27) ? lane : lane - 27;
        int c   = dm / 9;
        int rem = dm - 9 * c;
        int di  = rem / 3;
        int dj  = rem - 3 * di;
        int hh  = h + di - 1;
        int ww  = w + dj - 1;
        if (hh >= 0 && hh < 64 && ww >= 0 && ww < 64) {
            float v = x[((b * 3 + c) << 12) + (hh << 6) + ww];
            inp = (lane < 27) ? v : -v;
        }
    }

    const uint32_t inv_lane = (uint32_t)(63 - lane);

    #pragma unroll 1
    for (int g = 0; g < 2; ++g) {
        // ---- Phase 1: rank + packed scatter for 8 channels ----
        #pragma unroll 1
        for (int i = 0; i < 8; ++i) {
            const int nc = g * 8 + i;
            float mk   = (lane < 54) ? mask[nc * 54 + lane]   : 0.0f;
            float wv   = (lane < 54) ? weight[nc * 54 + lane] : 0.0f;
            float mxv  = (lane < 54) ? (inp + mk) : -INFINITY;
            float wsel = (wv > WOS_ZERO_TOL) ? wv : 0.0f;

            // Order-preserving uint32 map of float order (no NaNs here).
            int      bits = __float_as_int(mxv);
            uint32_t ob   = (uint32_t)(bits ^ ((bits >> 31) | 0x80000000));
            // 64-bit stable key: value major, (63-lane) minor -> distinct
            // keys; strict > reproduces jnp stable descending argsort.
            uint64_t myk  = ((uint64_t)ob << 32) | inv_lane;

            s_key[wid][lane] = myk;

            // rank = #{dp in 0..53 : key_dp > key_mine}; keys read in pairs
            // (b128) at wave-uniform addresses (hardware broadcast).
            const ulonglong2* kp =
                reinterpret_cast<const ulonglong2*>(&s_key[wid][0]);
            uint32_t rank = 0;
            #pragma unroll
            for (int dp = 0; dp < 27; ++dp) {
                ulonglong2 kk = kp[dp];
                rank += (kk.x > myk) ? 1u : 0u;
                rank += (kk.y > myk) ? 1u : 0u;
            }

            if (lane < 54) {
                s_wm[wid][i][rank] = make_float2(wsel, mxv);
            }
        }

        // ---- Phase 2: transposed sequential scan, lane -> channel ----
        {
            const int   nc8 = lane & 7;    // lanes 8..63 run redundant copies
            const float bv  = bias[g * 8 + nc8];
            float acc   = 0.0f;
            float ans   = 0.0f;
            bool  found = false;
            #pragma unroll
            for (int r = 0; r < 54; ++r) {
                float2 wm = s_wm[wid][nc8][r];
                acc += wm.x;                              // exact cumsum order
                bool nz   = (__float_as_int(wm.x) != 0);
                bool take = nz && (acc <= bv || !found);  // last nz <=bias,
                found     = found || nz;                  // else first nz
                ans       = take ? wm.y : ans;
            }
            if (lane < 8) out[p * 16 + g * 8 + lane] = ans;
        }
    }
}

extern "C" void kernel_launch(void* const* d_in, const int* in_sizes, int n_in,
                              void* d_out, int out_size, void* d_ws, size_t ws_size,
                              hipStream_t stream) {
    const float* x      = (const float*)d_in[0];
    const float* mask   = (const float*)d_in[1];
    const float* weight = (const float*)d_in[2];
    const float* bias   = (const float*)d_in[3];
    float* out = (float*)d_out;

    // 32768 pixels, 4 waves (pixels) per 256-thread block -> 8192 blocks
    wos_kernel<<<dim3(8192), dim3(256), 0, stream>>>(x, mask, weight, bias, out);
}

// Round 10
// 260.418 us; speedup vs baseline: 1.0539x; 1.0539x over previous
//
#include <hip/hip_runtime.h>
#include <limits.h>
#include <math.h>
#include <stdint.h>

#define WOS_ZERO_TOL 1e-6f
#define STRIDE 57   // odd stride: rows start on distinct bank pairs

// One wave (64 lanes) per pixel; nc processed in TWO groups of 8 so the
// sorted-column LDS array is half size -> 16.9 KB/block -> LDS allows 9
// blocks/CU, wave slots allow 8. NO VGPR cap: round 9's (256,8) bound made
// the compiler clamp to 32 VGPRs and spill ~4 KB/wave to scratch (WRITE_SIZE
// 2 MB -> 127 MB, +77 us). Round 8's natural pressure was 44 VGPR <= 64, so
// 8 blocks/CU is reachable with default bounds and no spills.
//
// Phase 1 (per nc in group): lane d owns candidate d (d<27: patch value,
//   d>=27: negated). Stable descending rank via u64 key
//   (ordered_float :: 63-lane) — bit-exact vs jnp stable argsort (verified
//   rounds 2/4/5/6/7/8/9). Keys broadcast through LDS (publish b64, read
//   back as ulonglong2/b128 at wave-uniform addresses, 27 reads); VALU per
//   pair = 2x (v_cmp_gt_u64 vcc + v_addc). Scatter float2{wsel,mxv} into
//   sorted column s_wm[wid][i][rank] with ONE ds_write_b64 (ranks distinct,
//   <=2-way bank alias = free on CDNA4).
// Phase 2 (per group, transposed): lane nc8 = lane&7 walks the 54 sorted
//   slots once — sequential f32 adds, association order identical to
//   np.cumsum. Selection in-loop: take = nz && (acc<=bias || !found) keeps
//   the LAST nz with acc<=bias, or the FIRST nz if none (acc monotone over
//   nz slots -> exactly the reference's clamped li). No final gather.
// Same-wave LDS RAW/WAR ordering (publish->read, scatter->scan, group 0->1
//   overwrite) is guaranteed by in-order per-wave LDS + compiler lgkmcnt.
__global__ __launch_bounds__(256) void wos_kernel(
    const float* __restrict__ x,       // (8,3,64,64)
    const float* __restrict__ mask,    // (16,54)
    const float* __restrict__ weight,  // (16,54)
    const float* __restrict__ bias,    // (16,1)
    float* __restrict__ out)           // flat: [pixel*16 + nc]
{
    __shared__ float2 s_wm[4][8][STRIDE];
    __shared__ unsigned long long s_key[4][64];

    const int lane = threadIdx.x & 63;
    const int wid  = threadIdx.x >> 6;
    const int p    = blockIdx.x * 4 + wid;   // pixel in [0, 32768)
    const int b    = p >> 12;
    const int l    = p & 4095;
    const int h    = l >> 6;
    const int w    = l & 63;

    // Gather this lane's patch value (zero padding at borders).
    float inp = 0.0f;
    if (lane < 54) {
        int dm  = (lane < 27) ? lane : lane - 27;
        int c   = dm / 9;
        int rem = dm - 9 * c;
        int di  = rem / 3;
        int dj  = rem - 3 * di;
        int hh  = h + di - 1;
        int ww  = w + dj - 1;
        if (hh >= 0 && hh < 64 && ww >= 0 && ww < 64) {
            float v = x[((b * 3 + c) << 12) + (hh << 6) + ww];
            inp = (lane < 27) ? v : -v;
        }
    }

    const uint32_t inv_lane = (uint32_t)(63 - lane);

    #pragma unroll 1
    for (int g = 0; g < 2; ++g) {
        // ---- Phase 1: rank + packed scatter for 8 channels ----
        #pragma unroll 1
        for (int i = 0; i < 8; ++i) {
            const int nc = g * 8 + i;
            float mk   = (lane < 54) ? mask[nc * 54 + lane]   : 0.0f;
            float wv   = (lane < 54) ? weight[nc * 54 + lane] : 0.0f;
            float mxv  = (lane < 54) ? (inp + mk) : -INFINITY;
            float wsel = (wv > WOS_ZERO_TOL) ? wv : 0.0f;

            // Order-preserving uint32 map of float order (no NaNs here).
            int      bits = __float_as_int(mxv);
            uint32_t ob   = (uint32_t)(bits ^ ((bits >> 31) | 0x80000000));
            // 64-bit stable key: value major, (63-lane) minor -> distinct
            // keys; strict > reproduces jnp stable descending argsort.
            uint64_t myk  = ((uint64_t)ob << 32) | inv_lane;

            s_key[wid][lane] = myk;

            // rank = #{dp in 0..53 : key_dp > key_mine}; keys read in pairs
            // (b128) at wave-uniform addresses (hardware broadcast).
            const ulonglong2* kp =
                reinterpret_cast<const ulonglong2*>(&s_key[wid][0]);
            uint32_t rank = 0;
            #pragma unroll
            for (int dp = 0; dp < 27; ++dp) {
                ulonglong2 kk = kp[dp];
                rank += (kk.x > myk) ? 1u : 0u;
                rank += (kk.y > myk) ? 1u : 0u;
            }

            if (lane < 54) {
                s_wm[wid][i][rank] = make_float2(wsel, mxv);
            }
        }

        // ---- Phase 2: transposed sequential scan, lane -> channel ----
        {
            const int   nc8 = lane & 7;    // lanes 8..63 run redundant copies
            const float bv  = bias[g * 8 + nc8];
            float acc   = 0.0f;
            float ans   = 0.0f;
            bool  found = false;
            #pragma unroll
            for (int r = 0; r < 54; ++r) {
                float2 wm = s_wm[wid][nc8][r];
                acc += wm.x;                              // exact cumsum order
                bool nz   = (__float_as_int(wm.x) != 0);
                bool take = nz && (acc <= bv || !found);  // last nz <=bias,
                found     = found || nz;                  // else first nz
                ans       = take ? wm.y : ans;
            }
            if (lane < 8) out[p * 16 + g * 8 + lane] = ans;
        }
    }
}

extern "C" void kernel_launch(void* const* d_in, const int* in_sizes, int n_in,
                              void* d_out, int out_size, void* d_ws, size_t ws_size,
                              hipStream_t stream) {
    const float* x      = (const float*)d_in[0];
    const float* mask   = (const float*)d_in[1];
    const float* weight = (const float*)d_in[2];
    const float* bias   = (const float*)d_in[3];
    float* out = (float*)d_out;

    // 32768 pixels, 4 waves (pixels) per 256-thread block -> 8192 blocks
    wos_kernel<<<dim3(8192), dim3(256), 0, stream>>>(x, mask, weight, bias, out);
}

// Round 13
// 218.869 us; speedup vs baseline: 1.2539x; 1.1898x over previous
//
#include <hip/hip_runtime.h>
#include <limits.h>
#include <math.h>
#include <stdint.h>

#define WOS_ZERO_TOL 1e-6f
#define STRIDE 57   // odd stride: 16 channel rows start on distinct banks

// One wave (64 lanes) per pixel. Lane d owns candidate d (d<27: patch value,
// d>=27: negated; lanes 54..63 idle with -inf).
//
// VERIFIED-EXACT semantics throughout (rounds 2/4/5/8, absmax 0.0):
//   u64 stable key = (ordered_float_bits(mx) << 32) | (63-lane); strict u64 >
//   reproduces jnp's stable descending argsort bit-exactly. No truncated-key
//   or tie-detection shortcuts (rounds 11/12 both failed on those).
//
// Round-13 perf levers (no semantic change):
//   1. All 16 channels' mask/weight loaded into registers BEFORE the loop:
//      32 loads issued back-to-back, one latency payment, instead of 16
//      exposed ~200-cyc waits inside the loop (round 8's VALUBusy gap).
//   2. TWO channels per pass: independent key arrays s_key[wid][0/1] and
//      independent rank chains -> 2x ILP in the compare loop.
//   3. LDS loads/stores use the SAME element type everywhere (no
//      reinterpret_cast) so no TBAA reordering hazard.
// Scatter wsel/mxv into sorted columns s_ws/s_mx[wid][nc][rank]
//   (ranks 0..53 distinct => <=2-way bank alias, free on CDNA4).
// Phase 2 (transposed, round-8 form): lane nc = lane&15 walks the 54 sorted
//   slots once — sequential f32 adds, association order identical to
//   np.cumsum. rstar = last r with (w!=0 && acc<=bias), fallback first-nz.
// Same-wave LDS RAW ordering (publish->read, scatter->scan) is guaranteed by
//   the in-order per-wave DS pipe + compiler lgkmcnt.
__global__ __launch_bounds__(256) void wos_kernel(
    const float* __restrict__ x,       // (8,3,64,64)
    const float* __restrict__ mask,    // (16,54)
    const float* __restrict__ weight,  // (16,54)
    const float* __restrict__ bias,    // (16,1)
    float* __restrict__ out)           // flat: [pixel*16 + nc]
{
    __shared__ float s_ws[4][16][STRIDE];
    __shared__ float s_mx[4][16][STRIDE];
    __shared__ unsigned long long s_key[4][2][64];

    const int lane = threadIdx.x & 63;
    const int wid  = threadIdx.x >> 6;
    const int p    = blockIdx.x * 4 + wid;   // pixel in [0, 32768)
    const int b    = p >> 12;
    const int l    = p & 4095;
    const int h    = l >> 6;
    const int w    = l & 63;

    // Gather this lane's patch value (zero padding at borders).
    float inp = 0.0f;
    if (lane < 54) {
        int dm  = (lane < 27) ? lane : lane - 27;
        int c   = dm / 9;
        int rem = dm - 9 * c;
        int di  = rem / 3;
        int dj  = rem - 3 * di;
        int hh  = h + di - 1;
        int ww  = w + dj - 1;
        if (hh >= 0 && hh < 64 && ww >= 0 && ww < 64) {
            float v = x[((b * 3 + c) << 12) + (hh << 6) + ww];
            inp = (lane < 27) ? v : -v;
        }
    }

    // Hoist ALL mask/weight loads: 32 independent loads, one wait.
    float mk[16], wv[16];
    #pragma unroll
    for (int nc = 0; nc < 16; ++nc) {
        mk[nc] = (lane < 54) ? mask[nc * 54 + lane]   : 0.0f;
        wv[nc] = (lane < 54) ? weight[nc * 54 + lane] : 0.0f;
    }

    const uint32_t inv_lane = (uint32_t)(63 - lane);

    // ---- Phase 1: rank + scatter, TWO channels per pass ----
    #pragma unroll 1
    for (int nc0 = 0; nc0 < 16; nc0 += 2) {
        float mxv0  = (lane < 54) ? (inp + mk[nc0])     : -INFINITY;
        float mxv1  = (lane < 54) ? (inp + mk[nc0 + 1]) : -INFINITY;
        float wsel0 = (wv[nc0]     > WOS_ZERO_TOL) ? wv[nc0]     : 0.0f;
        float wsel1 = (wv[nc0 + 1] > WOS_ZERO_TOL) ? wv[nc0 + 1] : 0.0f;

        // Order-preserving uint32 maps (no NaNs here).
        int      bits0 = __float_as_int(mxv0);
        int      bits1 = __float_as_int(mxv1);
        uint32_t ob0   = (uint32_t)(bits0 ^ ((bits0 >> 31) | 0x80000000));
        uint32_t ob1   = (uint32_t)(bits1 ^ ((bits1 >> 31) | 0x80000000));
        uint64_t k0    = ((uint64_t)ob0 << 32) | inv_lane;
        uint64_t k1    = ((uint64_t)ob1 << 32) | inv_lane;

        s_key[wid][0][lane] = k0;
        s_key[wid][1][lane] = k1;

        // rank = #{dp in 0..53 : key_dp > key_mine}; two independent
        // compare/accumulate chains (2x ILP), wave-uniform broadcast reads.
        uint32_t r0 = 0, r1 = 0;
        #pragma unroll
        for (int dp = 0; dp < 54; ++dp) {
            unsigned long long q0 = s_key[wid][0][dp];
            unsigned long long q1 = s_key[wid][1][dp];
            r0 += (q0 > k0) ? 1u : 0u;
            r1 += (q1 > k1) ? 1u : 0u;
        }

        if (lane < 54) {
            s_ws[wid][nc0][r0]     = wsel0;
            s_mx[wid][nc0][r0]     = mxv0;
            s_ws[wid][nc0 + 1][r1] = wsel1;
            s_mx[wid][nc0 + 1][r1] = mxv1;
        }
    }

    // ---- Phase 2: transposed sequential scan, lane = channel ----
    {
        const int   nc = lane & 15;       // lanes 16..63 run redundant copies
        const float bv = bias[nc];
        float acc   = 0.0f;
        int   rstar = -1;
        int   fnz   = 64;
        #pragma unroll
        for (int r = 0; r < 54; ++r) {
            float wr = s_ws[wid][nc][r];
            acc += wr;                                   // exact cumsum order
            bool nz = (__float_as_int(wr) != 0);
            rstar = (nz && acc <= bv) ? r : rstar;       // last nz with acc<=bias
            fnz   = (nz && r < fnz)   ? r : fnz;         // first nz (fallback)
        }
        if (rstar < 0) rstar = (fnz < 54) ? fnz : 0;     // fallback (rare)
        float ans = s_mx[wid][nc][rstar];
        if (lane < 16) out[p * 16 + lane] = ans;
    }
}

extern "C" void kernel_launch(void* const* d_in, const int* in_sizes, int n_in,
                              void* d_out, int out_size, void* d_ws, size_t ws_size,
                              hipStream_t stream) {
    const float* x      = (const float*)d_in[0];
    const float* mask   = (const float*)d_in[1];
    const float* weight = (const float*)d_in[2];
    const float* bias   = (const float*)d_in[3];
    float* out = (float*)d_out;

    // 32768 pixels, 4 waves (pixels) per 256-thread block -> 8192 blocks
    wos_kernel<<<dim3(8192), dim3(256), 0, stream>>>(x, mask, weight, bias, out);
}